// Round 2
// baseline (573.295 us; speedup 1.0000x reference)
//
#include <hip/hip_runtime.h>
#include <hip/hip_bf16.h>

// Palettized 3x3 VALID conv as implicit GEMM, round 2:
//   C[O=64, pix] = W[O, K=576] * A[K, pix],  K = (kh*3+kw)*64 + c
// Roles: weights = MFMA A-operand (M=O), pixels = B-operand (N=pix) so that
// C/D col = lane&15 = pixel -> contiguous-ow stores.
// WG = 512 threads = 8 waves; tile 4 oh x 64 ow x 64 O; each wave: 32 pixels x 64 O
//   -> acc 8 x f32x4 = 32 regs (halved vs round 1) -> target 3 WG/CU = 24 waves/CU.

typedef __bf16 bf16x8 __attribute__((ext_vector_type(8)));
typedef float f32x4 __attribute__((ext_vector_type(4)));

union Frag {
    uint4 q;
    bf16x8 v;
};

// ---- Weight dequant/swizzle into A-operand fragments (16x16x32 layout).
// Wg[(kc*4 + mt)*64 + lane], j=0..7:
//   o = mt*16 + (lane&15); c = (kc&1)*32 + (lane>>4)*8 + j; r = kc>>1; kh=r/3, kw=r%3
// (identical lane layout to round 1's verified B swizzle)
__global__ __launch_bounds__(256) void dequant_W(
        const float* __restrict__ lut, const int* __restrict__ widx,
        uint4* __restrict__ Wg) {
    int g = blockIdx.x * 256 + threadIdx.x;   // 0..4607
    int l = g & 63;
    int mt = (g >> 6) & 3;
    int kc = g >> 8;
    if (kc >= 18) return;
    int r = kc >> 1;
    int kh = r / 3, kw = r - kh * 3;
    int o = mt * 16 + (l & 15);
    int c0 = (kc & 1) * 32 + (l >> 4) * 8;
    Frag f;
#pragma unroll
    for (int j = 0; j < 8; ++j) {
        int c = c0 + j;
        int idx = widx[((o * 64 + c) * 3 + kh) * 3 + kw];
        f.v[j] = (__bf16)lut[idx];
    }
    Wg[g] = f.q;
}

// LDS: granule = 8 bf16 = channels cblk*8..+7 of pixel (row,col); idx = cblk*396 + row*66 + col
#define LDS_PIX 396

__global__ __launch_bounds__(512, 6) void conv_mfma(
        const float* __restrict__ x, const float* __restrict__ bias,
        const uint4* __restrict__ Wg, float* __restrict__ out) {
    __shared__ uint4 ldsA[8 * LDS_PIX];   // 50688 B -> 3 WGs/CU

    int bx = blockIdx.x;
    int ow0 = (bx & 3) * 64;          // 0,64,128,192
    int oh0 = ((bx >> 2) & 63) * 4;   // 0..252
    int n = bx >> 8;                  // 0..15
    int t = threadIdx.x;

    // ---- stage x[n, 0:64, oh0:oh0+6, ow0:ow0+66] -> LDS (fp32 -> bf16)
    {
        const float* xn = x + (size_t)n * (64 * 256 * 256);
        int col = t & 63;
        int cblk = t >> 6;            // 0..7, wave-uniform
        const float* base = xn + cblk * 8 * 65536 + ow0 + col;
#pragma unroll
        for (int rr = 0; rr < 6; ++rr) {
            int y = oh0 + rr; if (y > 255) y = 255;
            const float* src = base + y * 256;
            Frag f;
#pragma unroll
            for (int j = 0; j < 8; ++j)
                f.v[j] = (__bf16)src[j * 65536];
            ldsA[cblk * LDS_PIX + rr * 66 + col] = f.q;
        }
        // tail: cols 64,65 (8 cblk x 6 rows x 2 cols = 96 granules)
        if (t < 96) {
            int cb = t & 7;
            int rc = t >> 3;          // 0..11
            int rr = rc >> 1;
            int col2 = 64 + (rc & 1);
            int y = oh0 + rr; if (y > 255) y = 255;
            int xc = ow0 + col2; if (xc > 255) xc = 255;
            const float* src = xn + cb * 8 * 65536 + y * 256 + xc;
            Frag f;
#pragma unroll
            for (int j = 0; j < 8; ++j)
                f.v[j] = (__bf16)src[j * 65536];
            ldsA[cb * LDS_PIX + rr * 66 + col2] = f.q;
        }
    }
    __syncthreads();

    // ---- main GEMM: wave w owns pixels (oh row = w>>1 ... wait: ohl = w>>1, ow half = w&1)
    int w = t >> 6;                   // 0..7
    int l = t & 63;
    int l15 = l & 15, l4 = l >> 4;
    int ohl = w >> 1;                 // 0..3 output row within tile
    int owh = (w & 1) * 32;           // 0 or 32

    f32x4 acc[4][2] = {};             // [mt: O-tile][nt: 16-pixel group]

    const uint4* Wl = Wg + l;

#pragma unroll
    for (int kc = 0; kc < 18; ++kc) {
        const int h = kc & 1;
        const int r = kc >> 1;
        const int kh = r / 3, kw = r - kh * 3;
        int rowcol = (ohl + kh) * 66 + owh + l15 + kw;
        int cb = (h * 4 + l4) * LDS_PIX;

        Frag b[2];
        b[0].q = ldsA[cb + rowcol];
        b[1].q = ldsA[cb + rowcol + 16];

        Frag a[4];
#pragma unroll
        for (int mt = 0; mt < 4; ++mt)
            a[mt].q = Wl[(kc * 4 + mt) * 64];

#pragma unroll
        for (int mt = 0; mt < 4; ++mt)
#pragma unroll
            for (int nt = 0; nt < 2; ++nt)
                acc[mt][nt] = __builtin_amdgcn_mfma_f32_16x16x32_bf16(
                    a[mt].v, b[nt].v, acc[mt][nt], 0, 0, 0);
    }

    // ---- epilogue: C/D col = lane&15 = pixel, row = (lane>>4)*4+reg = O
    int oh = oh0 + ohl;
    if (oh < 254) {
        const float* outn = out + (size_t)n * (64 * 254 * 254);
        int owB = ow0 + owh + l15;
#pragma unroll
        for (int nt = 0; nt < 2; ++nt) {
            int ow = owB + nt * 16;
            if (ow < 254) {
#pragma unroll
                for (int mt = 0; mt < 4; ++mt) {
#pragma unroll
                    for (int rg = 0; rg < 4; ++rg) {
                        int o = mt * 16 + l4 * 4 + rg;
                        ((float*)outn)[(size_t)o * (254 * 254) + oh * 254 + ow] =
                            acc[mt][nt][rg] + bias[o];
                    }
                }
            }
        }
    }
}

extern "C" void kernel_launch(void* const* d_in, const int* in_sizes, int n_in,
                              void* d_out, int out_size, void* d_ws, size_t ws_size,
                              hipStream_t stream) {
    const float* x    = (const float*)d_in[0];
    const float* lut  = (const float*)d_in[1];
    const int*   widx = (const int*)d_in[2];
    const float* bias = (const float*)d_in[3];
    float* out = (float*)d_out;
    uint4* Wg = (uint4*)d_ws;   // 73728 B

    dequant_W<<<18, 256, 0, stream>>>(lut, widx, Wg);
    conv_mfma<<<4096, 512, 0, stream>>>(x, bias, (const uint4*)Wg, out);
}